// Round 3
// baseline (140.942 us; speedup 1.0000x reference)
//
#include <hip/hip_runtime.h>
#include <math.h>

#define BB 128   // batch
#define TT 8     // seq
#define DD 2048  // model dim
#define RR 4     // TT rank
#define VV 512   // vocab

typedef __attribute__((ext_vector_type(8))) short short8;
typedef __attribute__((ext_vector_type(4))) float v4f;

__device__ __forceinline__ unsigned pack_bf16(float x, float y) {
    union { float f; unsigned u; } a, b;
    a.f = x; b.f = y;
    unsigned ua = a.u + 0x7fffu + ((a.u >> 16) & 1u);
    unsigned ub = b.u + 0x7fffu + ((b.u >> 16) & 1u);
    return (ua >> 16) | (ub & 0xffff0000u);
}

// ---------------- phase A: T-mean -> fmb(bf16), alpha/beta partial dots ----------------
// grid 256 = (b, half-of-D). Partials written deterministically per (b,half); no atomics,
// no pre-zero needed. Also zeroes marg (replaces the memset dispatch).
__global__ __launch_bounds__(256) void phaseA(const float* __restrict__ inp,
                                              const float* __restrict__ w_alpha,
                                              const float* __restrict__ w_beta,
                                              unsigned short* __restrict__ fmb,
                                              float* __restrict__ alphaP,
                                              float* __restrict__ betaP,
                                              float* __restrict__ marg) {
    int bid = blockIdx.x;
    int b = bid >> 1, half = bid & 1;
    int tid = threadIdx.x;

    // zero marg (2048 floats) across blocks 0..7
    if (bid < 8) marg[bid * 256 + tid] = 0.f;

    const float* base = inp + (size_t)b * TT * DD;
    float pa[4] = {0.f, 0.f, 0.f, 0.f};
    float pb[4] = {0.f, 0.f, 0.f, 0.f};
#pragma unroll
    for (int i = 0; i < 4; ++i) {
        int d = half * 1024 + i * 256 + tid;
        float s = 0.f;
#pragma unroll
        for (int t = 0; t < TT; ++t) s += base[t * DD + d];
        float v = s * (1.0f / TT);
        union { float f; unsigned u; } cv; cv.f = v;
        unsigned r = cv.u + 0x7fffu + ((cv.u >> 16) & 1u);
        fmb[b * DD + d] = (unsigned short)(r >> 16);
        float4 wa = *(const float4*)(w_alpha + d * 4);
        float4 wb = *(const float4*)(w_beta + d * 4);
        pa[0] += v * wa.x; pa[1] += v * wa.y; pa[2] += v * wa.z; pa[3] += v * wa.w;
        pb[0] += v * wb.x; pb[1] += v * wb.y; pb[2] += v * wb.z; pb[3] += v * wb.w;
    }
#pragma unroll
    for (int r = 0; r < 4; ++r) {
        for (int m = 1; m < 64; m <<= 1) {
            pa[r] += __shfl_xor(pa[r], m);
            pb[r] += __shfl_xor(pb[r], m);
        }
    }
    __shared__ float sA[4][4], sB[4][4];
    int wid = tid >> 6;
    if ((tid & 63) == 0) {
#pragma unroll
        for (int r = 0; r < 4; ++r) { sA[wid][r] = pa[r]; sB[wid][r] = pb[r]; }
    }
    __syncthreads();
    if (tid < 4) {
        alphaP[b * 8 + half * 4 + tid] = sA[0][tid] + sA[1][tid] + sA[2][tid] + sA[3][tid];
        betaP [b * 8 + half * 4 + tid] = sB[0][tid] + sB[1][tid] + sB[2][tid] + sB[3][tid];
    }
}

// ---------------- phase B: bf16 MFMA GEMM + fused abs/marg/select epilogue ----------------
// v3: grid 512 (2 blocks/CU -> two independent barrier groups per CU hide each other's
// vmcnt stalls). Block nb covers 16 cols [nb*16, nb*16+16); K = 2048 in 8 chunks of 256.
// Depth-2 register prefetch with NAMED buffers (compile-time indices). XCD-pairing swizzle:
// blocks on one XCD cover a contiguous 1024-col slab of wv (L2 line + slab locality).
// Pad 268 (134 words, 134%32=6) spreads the 16 m15 rows across banks on ds_read_b128.
__global__ __launch_bounds__(512, 4) void phaseB(const unsigned short* __restrict__ fmb,
                                                 const float* __restrict__ wv,
                                                 const int* __restrict__ labels,
                                                 float* __restrict__ margA,
                                                 float* __restrict__ sel) {
    __shared__ unsigned short Ws[2][16][268];  // [buf][col][k+pad], bf16
    __shared__ int slab[BB * TT];

    const int tid = threadIdx.x;
    const int bid = blockIdx.x;
    const int nb = ((bid & 7) << 6) | (bid >> 3);  // XCD x -> contiguous blocks [64x, 64x+64)
    const int col0 = nb * 16;

    slab[tid] = labels[tid];
    slab[tid + 512] = labels[tid + 512];

    const int nq = tid & 3;        // float4 group within 16 cols
    const int kp = tid >> 2;       // 0..127 -> k pair 2kp, 2kp+1 within 256-chunk
    const int w = tid >> 6;        // wave
    const int lane = tid & 63;
    const int m15 = lane & 15;
    const int q = lane >> 4;

    const float* wbase = wv + (size_t)(2 * kp) * 8192 + col0 + nq * 4;
    const unsigned short* abase = fmb + (w * 16 + m15) * DD + q * 8;

    v4f acc = {0.f, 0.f, 0.f, 0.f};
    short8 afrA[8], afrB[8];       // A-frags for even / odd chunks
    float4 swA0, swA1, swB0, swB1; // wv reg buffers for even / odd chunks

    // prologue: load chunk0 -> swA, chunk1 -> swB; afrA <- chunk0; write chunk0 to Ws[0]
    swA0 = *(const float4*)(wbase);
    swA1 = *(const float4*)(wbase + 8192);
    {
        const float* p = wbase + (size_t)256 * 8192;
        swB0 = *(const float4*)(p);
        swB1 = *(const float4*)(p + 8192);
    }
#pragma unroll
    for (int ks = 0; ks < 8; ++ks) afrA[ks] = *(const short8*)(abase + ks * 32);
    {
        const float* f0 = (const float*)&swA0;
        const float* f1 = (const float*)&swA1;
#pragma unroll
        for (int j = 0; j < 4; ++j)
            *(unsigned*)&Ws[0][nq * 4 + j][2 * kp] = pack_bf16(f0[j], f1[j]);
    }
    __syncthreads();

#pragma unroll
    for (int i = 0; i < 4; ++i) {
        const int c0 = 2 * i;      // even step: MFMA chunk c0 from Ws[0]/afrA
        if (c0 < 6) {              // load chunk c0+2 -> swA
            const float* p = wbase + (size_t)(c0 + 2) * 256 * 8192;
            swA0 = *(const float4*)(p);
            swA1 = *(const float4*)(p + 8192);
        }
        {   // afrB <- chunk c0+1
            const unsigned short* ap = abase + (c0 + 1) * 256;
#pragma unroll
            for (int ks = 0; ks < 8; ++ks) afrB[ks] = *(const short8*)(ap + ks * 32);
        }
#pragma unroll
        for (int ks = 0; ks < 8; ++ks) {
            short8 b0 = *(const short8*)&Ws[0][m15][ks * 32 + q * 8];
            acc = __builtin_amdgcn_mfma_f32_16x16x32_bf16(afrA[ks], b0, acc, 0, 0, 0);
        }
        {   // write chunk c0+1 (swB, loaded ~1 step ago) -> Ws[1]
            const float* f0 = (const float*)&swB0;
            const float* f1 = (const float*)&swB1;
#pragma unroll
            for (int j = 0; j < 4; ++j)
                *(unsigned*)&Ws[1][nq * 4 + j][2 * kp] = pack_bf16(f0[j], f1[j]);
        }
        __syncthreads();

        const int c1 = 2 * i + 1;  // odd step: MFMA chunk c1 from Ws[1]/afrB
        if (c1 < 6) {              // load chunk c1+2 -> swB
            const float* p = wbase + (size_t)(c1 + 2) * 256 * 8192;
            swB0 = *(const float4*)(p);
            swB1 = *(const float4*)(p + 8192);
        }
        if (c1 < 7) {              // afrA <- chunk c1+1
            const unsigned short* ap = abase + (c1 + 1) * 256;
#pragma unroll
            for (int ks = 0; ks < 8; ++ks) afrA[ks] = *(const short8*)(ap + ks * 32);
        }
#pragma unroll
        for (int ks = 0; ks < 8; ++ks) {
            short8 b1 = *(const short8*)&Ws[1][m15][ks * 32 + q * 8];
            acc = __builtin_amdgcn_mfma_f32_16x16x32_bf16(afrB[ks], b1, acc, 0, 0, 0);
        }
        if (c1 < 7) {              // write chunk c1+1 (swA) -> Ws[0]
            const float* f0 = (const float*)&swA0;
            const float* f1 = (const float*)&swA1;
#pragma unroll
            for (int j = 0; j < 4; ++j)
                *(unsigned*)&Ws[0][nq * 4 + j][2 * kp] = pack_bf16(f0[j], f1[j]);
        }
        __syncthreads();
    }

    // epilogue: |acc| -> marg atomics + label-select scatter.
    // col = nb*16 + m15 = i_out*2048 + v*4 + j ; D layout: row = q*4+r, col = m15.
    const int i_out = nb >> 7;             // 0..3
    const int j = m15 & 3;
    const int v0 = (nb & 127) * 4 + (m15 >> 2);
    const float* ap = (const float*)&acc;
#pragma unroll
    for (int r = 0; r < 4; ++r) {
        int m = w * 16 + q * 4 + r;
        float a0 = fabsf(ap[r]);
        float s = a0;
        s += __shfl_xor(s, 4);
        s += __shfl_xor(s, 8);
        if ((lane & 12) == 0) atomicAdd(&margA[m * 16 + i_out * 4 + j], s);
#pragma unroll
        for (int t = 0; t < TT; ++t) {
            int lv = slab[m * 8 + t];
            if (lv == v0) sel[(m * 8 + t) * 16 + i_out * 4 + j] = a0;
        }
    }
}

// ---------------- phase D: chain products, normalizer, loss ----------------
__global__ __launch_bounds__(128) void phaseD(const float* __restrict__ alphaP,
                                              const float* __restrict__ betaP,
                                              const float* __restrict__ marg,
                                              const float* __restrict__ sel,
                                              float* __restrict__ out) {
    int b = threadIdx.x;
    const float* sb = sel + b * TT * 16;
    float res[16], tmp[16], mm[16], zm[16];
#pragma unroll
    for (int e = 0; e < 16; ++e) res[e] = sb[e];
    for (int t = 1; t < TT; ++t) {
        const float* m = sb + t * 16;
#pragma unroll
        for (int i = 0; i < 4; ++i)
#pragma unroll
            for (int jj = 0; jj < 4; ++jj) {
                float s = 0.f;
#pragma unroll
                for (int k = 0; k < 4; ++k) s += res[i * 4 + k] * m[k * 4 + jj];
                tmp[i * 4 + jj] = s;
            }
#pragma unroll
        for (int e = 0; e < 16; ++e) res[e] = tmp[e];
    }
#pragma unroll
    for (int e = 0; e < 16; ++e) { mm[e] = marg[b * 16 + e]; zm[e] = mm[e]; }
    for (int st = 0; st < TT; ++st) {
#pragma unroll
        for (int i = 0; i < 4; ++i)
#pragma unroll
            for (int jj = 0; jj < 4; ++jj) {
                float s = 0.f;
#pragma unroll
                for (int k = 0; k < 4; ++k) s += zm[i * 4 + k] * mm[k * 4 + jj];
                tmp[i * 4 + jj] = s;
            }
#pragma unroll
        for (int e = 0; e < 16; ++e) zm[e] = tmp[e];
    }
    float u = 0.f, z = 0.f;
#pragma unroll
    for (int i = 0; i < 4; ++i) {
        float ai = fabsf(alphaP[b * 8 + i] + alphaP[b * 8 + 4 + i]);
#pragma unroll
        for (int jj = 0; jj < 4; ++jj) {
            float bj = fabsf(betaP[b * 8 + jj] + betaP[b * 8 + 4 + jj]);
            u += ai * res[i * 4 + jj] * bj;
            z += ai * zm[i * 4 + jj] * bj;
        }
    }
    float loss = logf(z) - logf(u);
    __shared__ float red[128];
    red[b] = loss;
    __syncthreads();
    for (int off = 64; off >= 1; off >>= 1) {
        if (b < off) red[b] += red[b + off];
        __syncthreads();
    }
    if (b == 0) out[0] = red[0] * (1.0f / BB);
}

extern "C" void kernel_launch(void* const* d_in, const int* in_sizes, int n_in,
                              void* d_out, int out_size, void* d_ws, size_t ws_size,
                              hipStream_t stream) {
    const float* inp     = (const float*)d_in[0];  // [128,8,2048]
    const int*   labels  = (const int*)d_in[1];    // [128,8]
    const float* w_alpha = (const float*)d_in[2];  // [2048,4]
    const float* w_beta  = (const float*)d_in[3];  // [2048,4]
    const float* wv      = (const float*)d_in[4];  // [2048,8192]
    float* out = (float*)d_out;

    float* ws     = (float*)d_ws;
    float* alphaP = ws;                        // 1024  (per b,half,r partials)
    float* betaP  = ws + 1024;                 // 1024
    float* marg   = ws + 2048;                 // 2048  (zeroed by phaseA)
    float* sel    = ws + 4096;                 // 16384 (fully overwritten by phaseB)
    unsigned short* fmb = (unsigned short*)(ws + 20480);  // 128*2048 bf16

    phaseA<<<256, 256, 0, stream>>>(inp, w_alpha, w_beta, fmb, alphaP, betaP, marg);
    phaseB<<<512, 512, 0, stream>>>(fmb, wv, labels, marg, sel);
    phaseD<<<1, 128, 0, stream>>>(alphaP, betaP, marg, sel, out);
}

// Round 5
// 122.478 us; speedup vs baseline: 1.1508x; 1.1508x over previous
//
#include <hip/hip_runtime.h>
#include <math.h>

#define BB 128   // batch
#define TT 8     // seq
#define DD 2048  // model dim
#define RR 4     // TT rank
#define VV 512   // vocab

typedef __attribute__((ext_vector_type(8))) short short8;
typedef __attribute__((ext_vector_type(4))) float v4f;

__device__ __forceinline__ unsigned pack_bf16(float x, float y) {
    union { float f; unsigned u; } a, b;
    a.f = x; b.f = y;
    unsigned ua = a.u + 0x7fffu + ((a.u >> 16) & 1u);
    unsigned ub = b.u + 0x7fffu + ((b.u >> 16) & 1u);
    return (ua >> 16) | (ub & 0xffff0000u);
}

// ---------------- phase A: T-mean -> fmb(bf16), alpha/beta partial dots ----------------
// grid 256 = (b, half-of-D). Partials written deterministically per (b,half); no atomics.
__global__ __launch_bounds__(256) void phaseA(const float* __restrict__ inp,
                                              const float* __restrict__ w_alpha,
                                              const float* __restrict__ w_beta,
                                              unsigned short* __restrict__ fmb,
                                              float* __restrict__ alphaP,
                                              float* __restrict__ betaP) {
    int bid = blockIdx.x;
    int b = bid >> 1, half = bid & 1;
    int tid = threadIdx.x;

    const float* base = inp + (size_t)b * TT * DD;
    float pa[4] = {0.f, 0.f, 0.f, 0.f};
    float pb[4] = {0.f, 0.f, 0.f, 0.f};
#pragma unroll
    for (int i = 0; i < 4; ++i) {
        int d = half * 1024 + i * 256 + tid;
        float s = 0.f;
#pragma unroll
        for (int t = 0; t < TT; ++t) s += base[t * DD + d];
        float v = s * (1.0f / TT);
        union { float f; unsigned u; } cv; cv.f = v;
        unsigned r = cv.u + 0x7fffu + ((cv.u >> 16) & 1u);
        fmb[b * DD + d] = (unsigned short)(r >> 16);
        float4 wa = *(const float4*)(w_alpha + d * 4);
        float4 wb = *(const float4*)(w_beta + d * 4);
        pa[0] += v * wa.x; pa[1] += v * wa.y; pa[2] += v * wa.z; pa[3] += v * wa.w;
        pb[0] += v * wb.x; pb[1] += v * wb.y; pb[2] += v * wb.z; pb[3] += v * wb.w;
    }
#pragma unroll
    for (int r = 0; r < 4; ++r) {
        for (int m = 1; m < 64; m <<= 1) {
            pa[r] += __shfl_xor(pa[r], m);
            pb[r] += __shfl_xor(pb[r], m);
        }
    }
    __shared__ float sA[4][4], sB[4][4];
    int wid = tid >> 6;
    if ((tid & 63) == 0) {
#pragma unroll
        for (int r = 0; r < 4; ++r) { sA[wid][r] = pa[r]; sB[wid][r] = pb[r]; }
    }
    __syncthreads();
    if (tid < 4) {
        alphaP[b * 8 + half * 4 + tid] = sA[0][tid] + sA[1][tid] + sA[2][tid] + sA[3][tid];
        betaP [b * 8 + half * 4 + tid] = sB[0][tid] + sB[1][tid] + sB[2][tid] + sB[3][tid];
    }
}

// ---------------- phase B: bf16 MFMA GEMM, K-split x2 -> fp32 partial C ----------------
// v4b: round-2 hot loop verbatim (32-col blocks, chunk=128, afr[4] register-resident,
// depth-2 named prefetch) but grid 512 = 256 col-blocks x 2 K-halves -> 2 blocks/CU,
// two independent barrier groups per CU interleave their vmcnt stalls.
// Epilogue = plain fp32 partial-C stores (abs/marg/sel moved to phaseC).
__global__ __launch_bounds__(512, 4) void phaseB(const unsigned short* __restrict__ fmb,
                                                 const float* __restrict__ wv,
                                                 float* __restrict__ Cpart) {
    __shared__ unsigned short Ws[2][32][136];  // [buf][n][k+pad], bf16

    const int tid = threadIdx.x;
    const int bid = blockIdx.x;
    const int colb = bid & 255;
    const int half = bid >> 8;        // K-half: rows [half*1024, +1024)
    const int col0 = colb * 32;

    const int nq = tid & 7;        // float4 group within 32 cols
    const int kp = tid >> 3;       // 0..63 -> k pair 2kp, 2kp+1 within 128-chunk
    const int w = tid >> 6;        // wave
    const int lane = tid & 63;
    const int m15 = lane & 15;
    const int q = lane >> 4;

    const float* wbase = wv + (size_t)(half * 1024 + 2 * kp) * 8192 + col0 + nq * 4;
    const unsigned short* abase = fmb + (w * 16 + m15) * DD + half * 1024 + q * 8;

    v4f acc0 = {0.f, 0.f, 0.f, 0.f};
    v4f acc1 = {0.f, 0.f, 0.f, 0.f};
    short8 afrA[4], afrB[4];       // A-frags for even / odd chunks (32 VGPR - stays resident)
    float4 swA0, swA1, swB0, swB1; // wv reg buffers for even / odd chunks

    // prologue: load chunk0 -> swA, chunk1 -> swB; afrA <- chunk0; write chunk0 to Ws[0]
    swA0 = *(const float4*)(wbase);
    swA1 = *(const float4*)(wbase + 8192);
    {
        const float* p = wbase + (size_t)128 * 8192;
        swB0 = *(const float4*)(p);
        swB1 = *(const float4*)(p + 8192);
    }
#pragma unroll
    for (int ks = 0; ks < 4; ++ks) afrA[ks] = *(const short8*)(abase + ks * 32);
    {
        const float* f0 = (const float*)&swA0;
        const float* f1 = (const float*)&swA1;
#pragma unroll
        for (int j = 0; j < 4; ++j)
            *(unsigned*)&Ws[0][nq * 4 + j][2 * kp] = pack_bf16(f0[j], f1[j]);
    }
    __syncthreads();

#pragma unroll
    for (int i = 0; i < 4; ++i) {
        const int c0 = 2 * i;      // even step: MFMA chunk c0 from Ws[0]/afrA
        if (c0 < 6) {              // load chunk c0+2 -> swA
            const float* p = wbase + (size_t)(c0 + 2) * 128 * 8192;
            swA0 = *(const float4*)(p);
            swA1 = *(const float4*)(p + 8192);
        }
        {   // afrB <- chunk c0+1
            const unsigned short* ap = abase + (c0 + 1) * 128;
#pragma unroll
            for (int ks = 0; ks < 4; ++ks) afrB[ks] = *(const short8*)(ap + ks * 32);
        }
#pragma unroll
        for (int ks = 0; ks < 4; ++ks) {
            short8 b0 = *(const short8*)&Ws[0][m15][ks * 32 + q * 8];
            short8 b1 = *(const short8*)&Ws[0][16 + m15][ks * 32 + q * 8];
            acc0 = __builtin_amdgcn_mfma_f32_16x16x32_bf16(afrA[ks], b0, acc0, 0, 0, 0);
            acc1 = __builtin_amdgcn_mfma_f32_16x16x32_bf16(afrA[ks], b1, acc1, 0, 0, 0);
        }
        {   // write chunk c0+1 (swB) -> Ws[1]
            const float* f0 = (const float*)&swB0;
            const float* f1 = (const float*)&swB1;
#pragma unroll
            for (int j = 0; j < 4; ++j)
                *(unsigned*)&Ws[1][nq * 4 + j][2 * kp] = pack_bf16(f0[j], f1[j]);
        }
        __syncthreads();

        const int c1 = 2 * i + 1;  // odd step: MFMA chunk c1 from Ws[1]/afrB
        if (c1 < 6) {              // load chunk c1+2 -> swB
            const float* p = wbase + (size_t)(c1 + 2) * 128 * 8192;
            swB0 = *(const float4*)(p);
            swB1 = *(const float4*)(p + 8192);
        }
        if (c1 < 7) {              // afrA <- chunk c1+1
            const unsigned short* ap = abase + (c1 + 1) * 128;
#pragma unroll
            for (int ks = 0; ks < 4; ++ks) afrA[ks] = *(const short8*)(ap + ks * 32);
        }
#pragma unroll
        for (int ks = 0; ks < 4; ++ks) {
            short8 b0 = *(const short8*)&Ws[1][m15][ks * 32 + q * 8];
            short8 b1 = *(const short8*)&Ws[1][16 + m15][ks * 32 + q * 8];
            acc0 = __builtin_amdgcn_mfma_f32_16x16x32_bf16(afrB[ks], b0, acc0, 0, 0, 0);
            acc1 = __builtin_amdgcn_mfma_f32_16x16x32_bf16(afrB[ks], b1, acc1, 0, 0, 0);
        }
        if (c1 < 7) {              // write chunk c1+1 (swA) -> Ws[0]
            const float* f0 = (const float*)&swA0;
            const float* f1 = (const float*)&swA1;
#pragma unroll
            for (int j = 0; j < 4; ++j)
                *(unsigned*)&Ws[0][nq * 4 + j][2 * kp] = pack_bf16(f0[j], f1[j]);
        }
        __syncthreads();
    }

    // epilogue: raw fp32 partial-C stores. D layout: row = q*4+r, col = m15 (+16 for acc1).
    float* cbase = Cpart + (size_t)half * 128 * 8192 + col0 + m15;
    const float* a0p = (const float*)&acc0;
    const float* a1p = (const float*)&acc1;
#pragma unroll
    for (int r = 0; r < 4; ++r) {
        int row = w * 16 + q * 4 + r;
        cbase[(size_t)row * 8192]      = a0p[r];
        cbase[(size_t)row * 8192 + 16] = a1p[r];
    }
}

// ---------------- phase C: combine K-halves, abs, marg + label-select ----------------
// grid 128 (one block per m-row), 256 thr. marg written atomic-free via wave reduce
// (wave w == i-block since thread t covers cols [t*32, t*32+32) within i = t>>6).
__global__ __launch_bounds__(256) void phaseC(const float* __restrict__ Cpart,
                                              const int* __restrict__ labels,
                                              float* __restrict__ marg,
                                              float* __restrict__ sel) {
    const int m = blockIdx.x;
    const int tid = threadIdx.x;
    const float* r0 = Cpart + (size_t)m * 8192;
    const float* r1 = Cpart + (size_t)(128 + m) * 8192;

    float pj[4] = {0.f, 0.f, 0.f, 0.f};
    const int base = tid * 32;
#pragma unroll
    for (int g = 0; g < 8; ++g) {
        float4 a = *(const float4*)(r0 + base + g * 4);
        float4 b = *(const float4*)(r1 + base + g * 4);
        pj[0] += fabsf(a.x + b.x);
        pj[1] += fabsf(a.y + b.y);
        pj[2] += fabsf(a.z + b.z);
        pj[3] += fabsf(a.w + b.w);
    }
#pragma unroll
    for (int j = 0; j < 4; ++j)
        for (int s = 1; s < 64; s <<= 1) pj[j] += __shfl_xor(pj[j], s);
    const int lane = tid & 63;
    const int w = tid >> 6;   // == i block (cols [w*2048, +2048))
    if (lane == 0) {
#pragma unroll
        for (int j = 0; j < 4; ++j) marg[m * 16 + w * 4 + j] = pj[j];
    }

    if (tid < 128) {
        const int t = tid >> 4;          // 0..7
        const int ij = tid & 15;         // i*4+j
        const int i = ij >> 2, j = ij & 3;
        const int lv = labels[m * 8 + t];
        const int col = i * 2048 + lv * 4 + j;
        sel[(m * 8 + t) * 16 + ij] = fabsf(r0[col] + r1[col]);
    }
}

// ---------------- phase D: chain products, normalizer, loss ----------------
__global__ __launch_bounds__(128) void phaseD(const float* __restrict__ alphaP,
                                              const float* __restrict__ betaP,
                                              const float* __restrict__ marg,
                                              const float* __restrict__ sel,
                                              float* __restrict__ out) {
    int b = threadIdx.x;
    const float* sb = sel + b * TT * 16;
    float res[16], tmp[16], mm[16], zm[16];
#pragma unroll
    for (int e = 0; e < 16; ++e) res[e] = sb[e];
    for (int t = 1; t < TT; ++t) {
        const float* m = sb + t * 16;
#pragma unroll
        for (int i = 0; i < 4; ++i)
#pragma unroll
            for (int jj = 0; jj < 4; ++jj) {
                float s = 0.f;
#pragma unroll
                for (int k = 0; k < 4; ++k) s += res[i * 4 + k] * m[k * 4 + jj];
                tmp[i * 4 + jj] = s;
            }
#pragma unroll
        for (int e = 0; e < 16; ++e) res[e] = tmp[e];
    }
#pragma unroll
    for (int e = 0; e < 16; ++e) { mm[e] = marg[b * 16 + e]; zm[e] = mm[e]; }
    for (int st = 0; st < TT; ++st) {
#pragma unroll
        for (int i = 0; i < 4; ++i)
#pragma unroll
            for (int jj = 0; jj < 4; ++jj) {
                float s = 0.f;
#pragma unroll
                for (int k = 0; k < 4; ++k) s += zm[i * 4 + k] * mm[k * 4 + jj];
                tmp[i * 4 + jj] = s;
            }
#pragma unroll
        for (int e = 0; e < 16; ++e) zm[e] = tmp[e];
    }
    float u = 0.f, z = 0.f;
#pragma unroll
    for (int i = 0; i < 4; ++i) {
        float ai = fabsf(alphaP[b * 8 + i] + alphaP[b * 8 + 4 + i]);
#pragma unroll
        for (int jj = 0; jj < 4; ++jj) {
            float bj = fabsf(betaP[b * 8 + jj] + betaP[b * 8 + 4 + jj]);
            u += ai * res[i * 4 + jj] * bj;
            z += ai * zm[i * 4 + jj] * bj;
        }
    }
    float loss = logf(z) - logf(u);
    __shared__ float red[128];
    red[b] = loss;
    __syncthreads();
    for (int off = 64; off >= 1; off >>= 1) {
        if (b < off) red[b] += red[b + off];
        __syncthreads();
    }
    if (b == 0) out[0] = red[0] * (1.0f / BB);
}

extern "C" void kernel_launch(void* const* d_in, const int* in_sizes, int n_in,
                              void* d_out, int out_size, void* d_ws, size_t ws_size,
                              hipStream_t stream) {
    const float* inp     = (const float*)d_in[0];  // [128,8,2048]
    const int*   labels  = (const int*)d_in[1];    // [128,8]
    const float* w_alpha = (const float*)d_in[2];  // [2048,4]
    const float* w_beta  = (const float*)d_in[3];  // [2048,4]
    const float* wv      = (const float*)d_in[4];  // [2048,8192]
    float* out = (float*)d_out;

    float* ws     = (float*)d_ws;
    float* alphaP = ws;                        // 1024 floats (per b,half,r partials)
    float* betaP  = ws + 1024;                 // 1024 floats
    float* marg   = ws + 2048;                 // 2048 floats (written once by phaseC)
    float* sel    = ws + 4096;                 // 16384 floats (fully overwritten by phaseC)
    unsigned short* fmb = (unsigned short*)(ws + 20480);   // 128*2048 bf16 = 131072 floats
    float* Cpart  = ws + 151552;               // 2 x 128 x 8192 fp32 = 8 MB (PAST fmb!)

    phaseA<<<256, 256, 0, stream>>>(inp, w_alpha, w_beta, fmb, alphaP, betaP);
    phaseB<<<512, 512, 0, stream>>>(fmb, wv, Cpart);
    phaseC<<<128, 256, 0, stream>>>(Cpart, labels, marg, sel);
    phaseD<<<1, 128, 0, stream>>>(alphaP, betaP, marg, sel, out);
}

// Round 6
// 122.331 us; speedup vs baseline: 1.1521x; 1.0012x over previous
//
#include <hip/hip_runtime.h>
#include <math.h>

#define BB 128   // batch
#define TT 8     // seq
#define DD 2048  // model dim
#define RR 4     // TT rank
#define VV 512   // vocab

typedef __attribute__((ext_vector_type(8))) short short8;
typedef __attribute__((ext_vector_type(4))) float v4f;

// barrier WITHOUT the compiler's vmcnt(0) drain: ds ordering only (lgkmcnt(0)),
// global prefetch loads stay in flight across the barrier (T4, counted-vmcnt left
// to the compiler's dependency tracking). Single asm block => nothing can be
// scheduled between the wait and the barrier.
#define BARSYNC() asm volatile("s_waitcnt lgkmcnt(0)\n\ts_barrier" ::: "memory")

__device__ __forceinline__ unsigned pack_bf16(float x, float y) {
    union { float f; unsigned u; } a, b;
    a.f = x; b.f = y;
    unsigned ua = a.u + 0x7fffu + ((a.u >> 16) & 1u);
    unsigned ub = b.u + 0x7fffu + ((b.u >> 16) & 1u);
    return (ua >> 16) | (ub & 0xffff0000u);
}

// ---------------- phase A: T-mean -> fmb(bf16), alpha/beta partial dots ----------------
// grid 256 = (b, half-of-D). Partials written deterministically per (b,half); no atomics.
// Also zeroes marg (replaces the memset dispatch).
__global__ __launch_bounds__(256) void phaseA(const float* __restrict__ inp,
                                              const float* __restrict__ w_alpha,
                                              const float* __restrict__ w_beta,
                                              unsigned short* __restrict__ fmb,
                                              float* __restrict__ alphaP,
                                              float* __restrict__ betaP,
                                              float* __restrict__ marg) {
    int bid = blockIdx.x;
    int b = bid >> 1, half = bid & 1;
    int tid = threadIdx.x;

    // zero marg (2048 floats) across blocks 0..7
    if (bid < 8) marg[bid * 256 + tid] = 0.f;

    const float* base = inp + (size_t)b * TT * DD;
    float pa[4] = {0.f, 0.f, 0.f, 0.f};
    float pb[4] = {0.f, 0.f, 0.f, 0.f};
#pragma unroll
    for (int i = 0; i < 4; ++i) {
        int d = half * 1024 + i * 256 + tid;
        float s = 0.f;
#pragma unroll
        for (int t = 0; t < TT; ++t) s += base[t * DD + d];
        float v = s * (1.0f / TT);
        union { float f; unsigned u; } cv; cv.f = v;
        unsigned r = cv.u + 0x7fffu + ((cv.u >> 16) & 1u);
        fmb[b * DD + d] = (unsigned short)(r >> 16);
        float4 wa = *(const float4*)(w_alpha + d * 4);
        float4 wb = *(const float4*)(w_beta + d * 4);
        pa[0] += v * wa.x; pa[1] += v * wa.y; pa[2] += v * wa.z; pa[3] += v * wa.w;
        pb[0] += v * wb.x; pb[1] += v * wb.y; pb[2] += v * wb.z; pb[3] += v * wb.w;
    }
#pragma unroll
    for (int r = 0; r < 4; ++r) {
        for (int m = 1; m < 64; m <<= 1) {
            pa[r] += __shfl_xor(pa[r], m);
            pb[r] += __shfl_xor(pb[r], m);
        }
    }
    __shared__ float sA[4][4], sB[4][4];
    int wid = tid >> 6;
    if ((tid & 63) == 0) {
#pragma unroll
        for (int r = 0; r < 4; ++r) { sA[wid][r] = pa[r]; sB[wid][r] = pb[r]; }
    }
    __syncthreads();
    if (tid < 4) {
        alphaP[b * 8 + half * 4 + tid] = sA[0][tid] + sA[1][tid] + sA[2][tid] + sA[3][tid];
        betaP [b * 8 + half * 4 + tid] = sB[0][tid] + sB[1][tid] + sB[2][tid] + sB[3][tid];
    }
}

// ---------------- phase B: bf16 MFMA GEMM + fused abs/marg/select epilogue ----------------
// Round-2 structure verbatim (32-col blocks, chunk=128, afr[4] register-resident, depth-2
// named prefetch), but K-loop barriers are BARSYNC (no vmcnt(0) drain) so the depth-2 wv
// prefetch actually survives across barriers.
__global__ __launch_bounds__(512, 2) void phaseB(const unsigned short* __restrict__ fmb,
                                                 const float* __restrict__ wv,
                                                 const int* __restrict__ labels,
                                                 float* __restrict__ margA,
                                                 float* __restrict__ sel) {
    __shared__ unsigned short Ws[2][32][136];  // [buf][n][k+pad], bf16
    __shared__ int slab[BB * TT];

    const int tid = threadIdx.x;
    const int nb = blockIdx.x;
    const int col0 = nb * 32;

    slab[tid] = labels[tid];
    slab[tid + 512] = labels[tid + 512];

    const int nq = tid & 7;        // float4 group within 32 cols
    const int kp = tid >> 3;       // 0..63 -> k pair 2kp, 2kp+1 within 128-chunk
    const int w = tid >> 6;        // wave
    const int lane = tid & 63;
    const int m15 = lane & 15;
    const int q = lane >> 4;

    const float* wbase = wv + (size_t)(2 * kp) * 8192 + col0 + nq * 4;
    const unsigned short* abase = fmb + (w * 16 + m15) * DD + q * 8;

    v4f acc0 = {0.f, 0.f, 0.f, 0.f};
    v4f acc1 = {0.f, 0.f, 0.f, 0.f};
    short8 afrA[4], afrB[4];       // A-frags for even / odd chunks (register-resident)
    float4 swA0, swA1, swB0, swB1; // wv reg buffers for even / odd chunks

    // prologue: load chunk0 -> swA, chunk1 -> swB; afrA <- chunk0; write chunk0 to Ws[0]
    swA0 = *(const float4*)(wbase);
    swA1 = *(const float4*)(wbase + 8192);
    {
        const float* p = wbase + (size_t)128 * 8192;
        swB0 = *(const float4*)(p);
        swB1 = *(const float4*)(p + 8192);
    }
#pragma unroll
    for (int ks = 0; ks < 4; ++ks) afrA[ks] = *(const short8*)(abase + ks * 32);
    {
        const float* f0 = (const float*)&swA0;
        const float* f1 = (const float*)&swA1;
#pragma unroll
        for (int j = 0; j < 4; ++j)
            *(unsigned*)&Ws[0][nq * 4 + j][2 * kp] = pack_bf16(f0[j], f1[j]);
    }
    BARSYNC();   // keep swB (chunk1) load in flight

#pragma unroll
    for (int i = 0; i < 8; ++i) {
        const int c0 = 2 * i;      // even step: MFMA chunk c0 from Ws[0]/afrA
        if (c0 < 14) {             // load chunk c0+2 -> swA (stays in flight past barriers)
            const float* p = wbase + (size_t)(c0 + 2) * 128 * 8192;
            swA0 = *(const float4*)(p);
            swA1 = *(const float4*)(p + 8192);
        }
        {   // afrB <- chunk c0+1 (L2-resident fmb)
            const unsigned short* ap = abase + (c0 + 1) * 128;
#pragma unroll
            for (int ks = 0; ks < 4; ++ks) afrB[ks] = *(const short8*)(ap + ks * 32);
        }
#pragma unroll
        for (int ks = 0; ks < 4; ++ks) {
            short8 b0 = *(const short8*)&Ws[0][m15][ks * 32 + q * 8];
            short8 b1 = *(const short8*)&Ws[0][16 + m15][ks * 32 + q * 8];
            acc0 = __builtin_amdgcn_mfma_f32_16x16x32_bf16(afrA[ks], b0, acc0, 0, 0, 0);
            acc1 = __builtin_amdgcn_mfma_f32_16x16x32_bf16(afrA[ks], b1, acc1, 0, 0, 0);
        }
        {   // write chunk c0+1 (swB, loaded ~2 steps ago) -> Ws[1]
            const float* f0 = (const float*)&swB0;
            const float* f1 = (const float*)&swB1;
#pragma unroll
            for (int j = 0; j < 4; ++j)
                *(unsigned*)&Ws[1][nq * 4 + j][2 * kp] = pack_bf16(f0[j], f1[j]);
        }
        BARSYNC();

        const int c1 = 2 * i + 1;  // odd step: MFMA chunk c1 from Ws[1]/afrB
        if (c1 < 14) {             // load chunk c1+2 -> swB
            const float* p = wbase + (size_t)(c1 + 2) * 128 * 8192;
            swB0 = *(const float4*)(p);
            swB1 = *(const float4*)(p + 8192);
        }
        if (c1 < 15) {             // afrA <- chunk c1+1
            const unsigned short* ap = abase + (c1 + 1) * 128;
#pragma unroll
            for (int ks = 0; ks < 4; ++ks) afrA[ks] = *(const short8*)(ap + ks * 32);
        }
#pragma unroll
        for (int ks = 0; ks < 4; ++ks) {
            short8 b0 = *(const short8*)&Ws[1][m15][ks * 32 + q * 8];
            short8 b1 = *(const short8*)&Ws[1][16 + m15][ks * 32 + q * 8];
            acc0 = __builtin_amdgcn_mfma_f32_16x16x32_bf16(afrB[ks], b0, acc0, 0, 0, 0);
            acc1 = __builtin_amdgcn_mfma_f32_16x16x32_bf16(afrB[ks], b1, acc1, 0, 0, 0);
        }
        if (c1 < 15) {             // write chunk c1+1 (swA) -> Ws[0]
            const float* f0 = (const float*)&swA0;
            const float* f1 = (const float*)&swA1;
#pragma unroll
            for (int j = 0; j < 4; ++j)
                *(unsigned*)&Ws[0][nq * 4 + j][2 * kp] = pack_bf16(f0[j], f1[j]);
        }
        BARSYNC();
    }

    // epilogue: |acc| -> marg atomics + label-select scatter. D layout: row=q*4+r, col=m15.
    const int vbase = (nb & 63) * 8;
    const int iblk = nb >> 6;
    const int j = m15 & 3;
    const int v0 = vbase + (m15 >> 2);   // col = m15
    const float* a0p = (const float*)&acc0;
    const float* a1p = (const float*)&acc1;
#pragma unroll
    for (int r = 0; r < 4; ++r) {
        int m = w * 16 + q * 4 + r;
        float a0 = fabsf(a0p[r]);        // col = m15       -> v0
        float a1 = fabsf(a1p[r]);        // col = 16 + m15  -> v0 + 4
        float s = a0 + a1;
        s += __shfl_xor(s, 4);
        s += __shfl_xor(s, 8);
        if ((lane & 12) == 0) atomicAdd(&margA[m * 16 + iblk * 4 + j], s);
#pragma unroll
        for (int t = 0; t < TT; ++t) {
            int lv = slab[m * 8 + t];
            if (lv == v0)     sel[(m * 8 + t) * 16 + iblk * 4 + j] = a0;
            if (lv == v0 + 4) sel[(m * 8 + t) * 16 + iblk * 4 + j] = a1;
        }
    }
}

// ---------------- phase D: chain products, normalizer, loss ----------------
__global__ __launch_bounds__(128) void phaseD(const float* __restrict__ alphaP,
                                              const float* __restrict__ betaP,
                                              const float* __restrict__ marg,
                                              const float* __restrict__ sel,
                                              float* __restrict__ out) {
    int b = threadIdx.x;
    const float* sb = sel + b * TT * 16;
    float res[16], tmp[16], mm[16], zm[16];
#pragma unroll
    for (int e = 0; e < 16; ++e) res[e] = sb[e];
    for (int t = 1; t < TT; ++t) {
        const float* m = sb + t * 16;
#pragma unroll
        for (int i = 0; i < 4; ++i)
#pragma unroll
            for (int jj = 0; jj < 4; ++jj) {
                float s = 0.f;
#pragma unroll
                for (int k = 0; k < 4; ++k) s += res[i * 4 + k] * m[k * 4 + jj];
                tmp[i * 4 + jj] = s;
            }
#pragma unroll
        for (int e = 0; e < 16; ++e) res[e] = tmp[e];
    }
#pragma unroll
    for (int e = 0; e < 16; ++e) { mm[e] = marg[b * 16 + e]; zm[e] = mm[e]; }
    for (int st = 0; st < TT; ++st) {
#pragma unroll
        for (int i = 0; i < 4; ++i)
#pragma unroll
            for (int jj = 0; jj < 4; ++jj) {
                float s = 0.f;
#pragma unroll
                for (int k = 0; k < 4; ++k) s += zm[i * 4 + k] * mm[k * 4 + jj];
                tmp[i * 4 + jj] = s;
            }
#pragma unroll
        for (int e = 0; e < 16; ++e) zm[e] = tmp[e];
    }
    float u = 0.f, z = 0.f;
#pragma unroll
    for (int i = 0; i < 4; ++i) {
        float ai = fabsf(alphaP[b * 8 + i] + alphaP[b * 8 + 4 + i]);
#pragma unroll
        for (int jj = 0; jj < 4; ++jj) {
            float bj = fabsf(betaP[b * 8 + jj] + betaP[b * 8 + 4 + jj]);
            u += ai * res[i * 4 + jj] * bj;
            z += ai * zm[i * 4 + jj] * bj;
        }
    }
    float loss = logf(z) - logf(u);
    __shared__ float red[128];
    red[b] = loss;
    __syncthreads();
    for (int off = 64; off >= 1; off >>= 1) {
        if (b < off) red[b] += red[b + off];
        __syncthreads();
    }
    if (b == 0) out[0] = red[0] * (1.0f / BB);
}

extern "C" void kernel_launch(void* const* d_in, const int* in_sizes, int n_in,
                              void* d_out, int out_size, void* d_ws, size_t ws_size,
                              hipStream_t stream) {
    const float* inp     = (const float*)d_in[0];  // [128,8,2048]
    const int*   labels  = (const int*)d_in[1];    // [128,8]
    const float* w_alpha = (const float*)d_in[2];  // [2048,4]
    const float* w_beta  = (const float*)d_in[3];  // [2048,4]
    const float* wv      = (const float*)d_in[4];  // [2048,8192]
    float* out = (float*)d_out;

    float* ws     = (float*)d_ws;
    float* alphaP = ws;                        // 1024 floats (per b,half,r partials)
    float* betaP  = ws + 1024;                 // 1024 floats
    float* marg   = ws + 2048;                 // 2048 floats (zeroed by phaseA)
    float* sel    = ws + 4096;                 // 16384 floats (fully overwritten by phaseB)
    unsigned short* fmb = (unsigned short*)(ws + 20480);  // 128*2048 bf16 = 131072 floats

    phaseA<<<256, 256, 0, stream>>>(inp, w_alpha, w_beta, fmb, alphaP, betaP, marg);
    phaseB<<<256, 512, 0, stream>>>(fmb, wv, labels, marg, sel);
    phaseD<<<1, 128, 0, stream>>>(alphaP, betaP, marg, sel, out);
}